// Round 1
// baseline (391.262 us; speedup 1.0000x reference)
//
#include <hip/hip_runtime.h>
#include <math.h>

// Element-wise physics step, B = 8,388,608 rows.
// Memory-bound: ~503 MB total HBM traffic -> ~80-100 us roofline at 6.3 TB/s.
// Numerics deliberately mirror numpy f32 op-by-op (no FMA contraction in the
// critical chain) so the boolean reached_target boundary matches the ref.

__global__ __launch_bounds__(256) void step_kernel(
    const float* __restrict__ x,        // (B,5)
    const float* __restrict__ a,        // (B,2)
    const float* __restrict__ noise,    // (B,2)
    const float* __restrict__ pro_gains,          // (2,)
    const float* __restrict__ pro_noise_ln_vars,  // (2,)
    const float* __restrict__ goal_radius,        // (1,)
    float* __restrict__ out_next,       // (B,5) at d_out
    float* __restrict__ out_reach,      // (B,)  at d_out + 5*B
    int n)
{
    int i = blockIdx.x * blockDim.x + threadIdx.x;
    if (i >= n) return;

    // Uniform scalars (L1/sL1-cached; compiler hoists to scalar loads).
    const float g0 = pro_gains[0];
    const float g1 = pro_gains[1];
    const float std0 = __fsqrt_rn(expf(pro_noise_ln_vars[0]));
    const float std1 = __fsqrt_rn(expf(pro_noise_ln_vars[1]));
    const float gr = goal_radius[0];

    const size_t si = (size_t)i;
    const float2 av = *(const float2*)(a + 2 * si);
    const float2 nv = *(const float2*)(noise + 2 * si);
    const float px0  = x[5 * si + 0];
    const float py0  = x[5 * si + 1];
    const float ang0 = x[5 * si + 2];

    // vel = g0*a0 + std0*n0 ; ang_vel = g1*a1 + std1*n1  (no fma, numpy order)
    const float w0 = __fmul_rn(std0, nv.x);
    const float w1 = __fmul_rn(std1, nv.y);
    const float vel     = __fadd_rn(__fmul_rn(g0, av.x), w0);
    const float ang_vel = __fadd_rn(__fmul_rn(g1, av.y), w1);

    const float DT     = 0.1f;
    const float PI_F   = 3.14159265358979323846f;  // rounds to 3.14159274f
    const float TWOPI  = 6.283185307179586f;       // rounds to 6.2831855f

    // ang = mod(ang0 + ang_vel*DT + pi, 2pi) - pi   (numpy mod: sign of divisor)
    const float t  = __fadd_rn(ang0, __fmul_rn(ang_vel, DT));
    const float tp = __fadd_rn(t, PI_F);
    float m = fmodf(tp, TWOPI);
    if (m < 0.0f) m = __fadd_rn(m, TWOPI);
    const float ang = __fsub_rn(m, PI_F);

    float s, c;
    sincosf(ang, &s, &c);  // accurate variant (~2 ulp), matches np closely

    // px = clip(px0 + (vel*cos)*DT, -1, 1) ; same for py with sin
    float px = __fadd_rn(px0, __fmul_rn(__fmul_rn(vel, c), DT));
    px = fminf(fmaxf(px, -1.0f), 1.0f);
    float py = __fadd_rn(py0, __fmul_rn(__fmul_rn(vel, s), DT));
    py = fminf(fmaxf(py, -1.0f), 1.0f);

    // reached = sqrt(px^2 + py^2) <= goal_radius
    const float r2 = __fadd_rn(__fmul_rn(px, px), __fmul_rn(py, py));
    const float r  = __fsqrt_rn(r2);

    out_next[5 * si + 0] = px;
    out_next[5 * si + 1] = py;
    out_next[5 * si + 2] = ang;
    out_next[5 * si + 3] = vel;
    out_next[5 * si + 4] = ang_vel;
    out_reach[si] = (r <= gr) ? 1.0f : 0.0f;
}

extern "C" void kernel_launch(void* const* d_in, const int* in_sizes, int n_in,
                              void* d_out, int out_size, void* d_ws, size_t ws_size,
                              hipStream_t stream) {
    const float* x      = (const float*)d_in[0];
    const float* a      = (const float*)d_in[1];
    const float* noise  = (const float*)d_in[2];
    const float* gains  = (const float*)d_in[3];
    const float* lnvars = (const float*)d_in[4];
    const float* gradius= (const float*)d_in[5];

    const int n = in_sizes[0] / 5;            // B
    float* out_next  = (float*)d_out;         // B*5 floats
    float* out_reach = (float*)d_out + (size_t)n * 5;  // B floats

    const int block = 256;
    const int grid = (n + block - 1) / block;
    step_kernel<<<grid, block, 0, stream>>>(x, a, noise, gains, lnvars, gradius,
                                            out_next, out_reach, n);
}